// Round 4
// baseline (388.342 us; speedup 1.0000x reference)
//
#include <hip/hip_runtime.h>

// GRU: H=32, I=1, B=2048, T=1024, fused output Linear(32,1).
// Mapping: 1 batch per 64-lane wave (2048 waves = 2/SIMD). Lane (half, j)
// owns gate rows {r,z,n} of unit j for K-range [16*half, 16*half+16).
// v4: force weight residency with an asm "+v" pin (defeats the allocator's
// remat/reload of the 48 weight VGPRs that kept VGPR_Count at 52 and added
// ~90 VALU instrs/step in v2/v3). Also: log2(e) folded into weights/biases
// (saves 3 muls/step + shortens the gate chain), each gate's K-chain split
// 2x8 for ILP, y-stash junk region removed (both halves write identical h).

constexpr int H  = 32;
constexpr int TT = 1024;
constexpr int BB = 2048;

__device__ __forceinline__ float rcp_(float a)  { return __builtin_amdgcn_rcpf(a); }
__device__ __forceinline__ float exp2_(float a) { return __builtin_amdgcn_exp2f(a); }
__device__ __forceinline__ float bperm_(int bp, float v) {
    return __uint_as_float((unsigned)__builtin_amdgcn_ds_bpermute(bp, (int)__float_as_uint(v)));
}

__global__ __launch_bounds__(256, 2)
void gru_fused(const float* __restrict__ x,      // [B,T]
               const float* __restrict__ h0,     // [1,B,H]
               const float* __restrict__ W_ih,   // [3H,1]
               const float* __restrict__ W_hh,   // [3H,H]
               const float* __restrict__ b_ih,   // [3H]
               const float* __restrict__ b_hh,   // [3H]
               const float* __restrict__ W_out,  // [1,H]
               const float* __restrict__ b_out,  // [1]
               float* __restrict__ out)          // y[B,T] ++ h_n[B,H]
{
    __shared__ __align__(16) float hbuf[4][64];    // [wave][2 copies of h]
    __shared__ float ybuf[4][33 * 32];             // y transpose, 33-stride

    const int tid  = threadIdx.x;
    const int w    = tid >> 6;
    const int lane = tid & 63;
    const int half = lane >> 5;
    const int j    = lane & 31;
    const int b    = (blockIdx.x << 2) | w;

    const float NL2E = -1.44269504f;   // -log2(e): folded into r,z weights
    const float P2L2 =  2.88539008f;   //  2*log2(e): folded into n weights

    // --- weights: own K-half of rows {j, H+j, 2H+j}, pre-scaled ---
    const float* Wrp = &W_hh[(0 * H + j) * H + 16 * half];
    const float* Wzp = &W_hh[(1 * H + j) * H + 16 * half];
    const float* Wnp = &W_hh[(2 * H + j) * H + 16 * half];
    float Wr[16], Wz[16], Wn[16];
#pragma unroll
    for (int k = 0; k < 4; ++k) {
        float4 a = ((const float4*)Wrp)[k];
        float4 c = ((const float4*)Wzp)[k];
        float4 d = ((const float4*)Wnp)[k];
        Wr[4*k+0] = a.x * NL2E; Wr[4*k+1] = a.y * NL2E; Wr[4*k+2] = a.z * NL2E; Wr[4*k+3] = a.w * NL2E;
        Wz[4*k+0] = c.x * NL2E; Wz[4*k+1] = c.y * NL2E; Wz[4*k+2] = c.z * NL2E; Wz[4*k+3] = c.w * NL2E;
        Wn[4*k+0] = d.x * P2L2; Wn[4*k+1] = d.y * P2L2; Wn[4*k+2] = d.z * P2L2; Wn[4*k+3] = d.w * P2L2;
    }
    // bias / input-weight terms enter accumulators once (zero on half1)
    float wir = half ? 0.0f : (W_ih[j] * NL2E);
    float wiz = half ? 0.0f : (W_ih[H + j] * NL2E);
    float br  = half ? 0.0f : ((b_ih[j] + b_hh[j]) * NL2E);
    float bz  = half ? 0.0f : ((b_ih[H + j] + b_hh[H + j]) * NL2E);
    float bhn = half ? 0.0f : (b_hh[2 * H + j] * P2L2);
    float win = W_ih[2 * H + j] * P2L2;
    float bin = b_ih[2 * H + j] * P2L2;
    float wo  = W_out[j];
    const float bo = b_out[0];

    // ---- pin: values become asm-defined; remat/reload is now illegal ----
    asm volatile("" :
        "+v"(Wr[0]), "+v"(Wr[1]), "+v"(Wr[2]), "+v"(Wr[3]),
        "+v"(Wr[4]), "+v"(Wr[5]), "+v"(Wr[6]), "+v"(Wr[7]),
        "+v"(Wr[8]), "+v"(Wr[9]), "+v"(Wr[10]), "+v"(Wr[11]),
        "+v"(Wr[12]), "+v"(Wr[13]), "+v"(Wr[14]), "+v"(Wr[15]),
        "+v"(Wz[0]), "+v"(Wz[1]), "+v"(Wz[2]), "+v"(Wz[3]),
        "+v"(Wz[4]), "+v"(Wz[5]), "+v"(Wz[6]), "+v"(Wz[7]),
        "+v"(Wz[8]), "+v"(Wz[9]), "+v"(Wz[10]), "+v"(Wz[11]),
        "+v"(Wz[12]), "+v"(Wz[13]), "+v"(Wz[14]), "+v"(Wz[15]),
        "+v"(Wn[0]), "+v"(Wn[1]), "+v"(Wn[2]), "+v"(Wn[3]),
        "+v"(Wn[4]), "+v"(Wn[5]), "+v"(Wn[6]), "+v"(Wn[7]),
        "+v"(Wn[8]), "+v"(Wn[9]), "+v"(Wn[10]), "+v"(Wn[11]),
        "+v"(Wn[12]), "+v"(Wn[13]), "+v"(Wn[14]), "+v"(Wn[15]));
    asm volatile("" :
        "+v"(wir), "+v"(wiz), "+v"(br), "+v"(bz),
        "+v"(bhn), "+v"(win), "+v"(bin), "+v"(wo));

    float h = h0[b * H + j];

    const float* xb = x + (size_t)b * TT;
    float*       yb = out + (size_t)b * TT;

    float* hw = &hbuf[w][0];
    // half0 reads words 0..15 (h_0..h_15), half1 words 48..63 (h_16..h_31):
    // disjoint bank groups, conflict-free.
    const float4* hp = (const float4*)&hbuf[w][48 * half];
    // y transpose: both halves write the SAME value (h identical post-combine)
    // to the same address -> benign; banks (s+j)&31 distinct across j.
    float* yw = &ybuf[w][j];
    float* yrow = &ybuf[w][0];

    const int bp = (lane ^ 32) << 2;   // ds_bpermute byte addr (xor-32 swap)

#pragma unroll 1
    for (int t0 = 0; t0 < TT; t0 += 32) {
        const float xv = xb[t0 + j];   // lane j holds x[t0+j]

#pragma unroll
        for (int s = 0; s < 32; ++s) {
            hw[lane] = h;
            __builtin_amdgcn_wave_barrier();
            const float4 q0 = hp[0], q1 = hp[1], q2 = hp[2], q3 = hp[3];

            const float xt = __uint_as_float(
                (unsigned)__builtin_amdgcn_readlane((int)__float_as_uint(xv), s));

            // two 8-deep sub-chains per gate (ILP 6)
            float r0 = __builtin_fmaf(xt, wir, br);
            float z0 = __builtin_fmaf(xt, wiz, bz);
            float n0 = bhn;
            r0 = __builtin_fmaf(Wr[0], q0.x, r0); r0 = __builtin_fmaf(Wr[1], q0.y, r0);
            r0 = __builtin_fmaf(Wr[2], q0.z, r0); r0 = __builtin_fmaf(Wr[3], q0.w, r0);
            r0 = __builtin_fmaf(Wr[4], q1.x, r0); r0 = __builtin_fmaf(Wr[5], q1.y, r0);
            r0 = __builtin_fmaf(Wr[6], q1.z, r0); r0 = __builtin_fmaf(Wr[7], q1.w, r0);
            z0 = __builtin_fmaf(Wz[0], q0.x, z0); z0 = __builtin_fmaf(Wz[1], q0.y, z0);
            z0 = __builtin_fmaf(Wz[2], q0.z, z0); z0 = __builtin_fmaf(Wz[3], q0.w, z0);
            z0 = __builtin_fmaf(Wz[4], q1.x, z0); z0 = __builtin_fmaf(Wz[5], q1.y, z0);
            z0 = __builtin_fmaf(Wz[6], q1.z, z0); z0 = __builtin_fmaf(Wz[7], q1.w, z0);
            n0 = __builtin_fmaf(Wn[0], q0.x, n0); n0 = __builtin_fmaf(Wn[1], q0.y, n0);
            n0 = __builtin_fmaf(Wn[2], q0.z, n0); n0 = __builtin_fmaf(Wn[3], q0.w, n0);
            n0 = __builtin_fmaf(Wn[4], q1.x, n0); n0 = __builtin_fmaf(Wn[5], q1.y, n0);
            n0 = __builtin_fmaf(Wn[6], q1.z, n0); n0 = __builtin_fmaf(Wn[7], q1.w, n0);

            float r1 = Wr[8] * q2.x;
            float z1 = Wz[8] * q2.x;
            float n1 = Wn[8] * q2.x;
            r1 = __builtin_fmaf(Wr[9],  q2.y, r1); r1 = __builtin_fmaf(Wr[10], q2.z, r1);
            r1 = __builtin_fmaf(Wr[11], q2.w, r1);
            r1 = __builtin_fmaf(Wr[12], q3.x, r1); r1 = __builtin_fmaf(Wr[13], q3.y, r1);
            r1 = __builtin_fmaf(Wr[14], q3.z, r1); r1 = __builtin_fmaf(Wr[15], q3.w, r1);
            z1 = __builtin_fmaf(Wz[9],  q2.y, z1); z1 = __builtin_fmaf(Wz[10], q2.z, z1);
            z1 = __builtin_fmaf(Wz[11], q2.w, z1);
            z1 = __builtin_fmaf(Wz[12], q3.x, z1); z1 = __builtin_fmaf(Wz[13], q3.y, z1);
            z1 = __builtin_fmaf(Wz[14], q3.z, z1); z1 = __builtin_fmaf(Wz[15], q3.w, z1);
            n1 = __builtin_fmaf(Wn[9],  q2.y, n1); n1 = __builtin_fmaf(Wn[10], q2.z, n1);
            n1 = __builtin_fmaf(Wn[11], q2.w, n1);
            n1 = __builtin_fmaf(Wn[12], q3.x, n1); n1 = __builtin_fmaf(Wn[13], q3.y, n1);
            n1 = __builtin_fmaf(Wn[14], q3.z, n1); n1 = __builtin_fmaf(Wn[15], q3.w, n1);

            float accr = r0 + r1;
            float accz = z0 + z1;
            float accn = n0 + n1;

            // combine the two K-halves (xor-32 swap + add)
            accr += bperm_(bp, accr);
            accz += bperm_(bp, accz);
            accn += bperm_(bp, accn);

            // gates: scales pre-folded; sigmoid = rcp(1+exp2(acc'))
            const float r = rcp_(1.0f + exp2_(accr));
            const float z = rcp_(1.0f + exp2_(accz));
            const float xpn  = __builtin_fmaf(xt, win, bin);
            const float npre = __builtin_fmaf(r, accn, xpn);      // = 2*log2(e)*npre
            const float n = __builtin_fmaf(-2.0f, rcp_(1.0f + exp2_(npre)), 1.0f);

            h = __builtin_fmaf(z, h - n, n);   // (1-z)*n + z*h

            yw[33 * s] = wo * h;               // constant-offset ds_write
        }

        // amortized y reduction: lane (half,j) sums row j (broadcast across halves)
        __builtin_amdgcn_wave_barrier();
        float s0 = 0.0f, s1 = 0.0f, s2 = 0.0f, s3 = 0.0f;
#pragma unroll
        for (int k = 0; k < 32; k += 4) {
            s0 += yrow[33 * j + k + 0];
            s1 += yrow[33 * j + k + 1];
            s2 += yrow[33 * j + k + 2];
            s3 += yrow[33 * j + k + 3];
        }
        if (half == 0) {
            yb[t0 + j] = (s0 + s1) + (s2 + s3) + bo;
        }
        __builtin_amdgcn_wave_barrier();   // next chunk's writes must not pass reads
    }

    if (half == 0) {
        out[(size_t)BB * TT + b * H + j] = h;   // h_n
    }
}

extern "C" void kernel_launch(void* const* d_in, const int* in_sizes, int n_in,
                              void* d_out, int out_size, void* d_ws, size_t ws_size,
                              hipStream_t stream) {
    const float* x     = (const float*)d_in[0];
    const float* h0    = (const float*)d_in[1];
    const float* W_ih  = (const float*)d_in[2];
    const float* W_hh  = (const float*)d_in[3];
    const float* b_ih  = (const float*)d_in[4];
    const float* b_hh  = (const float*)d_in[5];
    const float* W_out = (const float*)d_in[6];
    const float* b_out = (const float*)d_in[7];
    float* out = (float*)d_out;

    dim3 grid(BB / 4);   // 512 blocks, 4 waves (batches) each
    dim3 block(256);
    gru_fused<<<grid, block, 0, stream>>>(x, h0, W_ih, W_hh, b_ih, b_hh,
                                          W_out, b_out, out);
}

// Round 5
// 369.872 us; speedup vs baseline: 1.0499x; 1.0499x over previous
//
#include <hip/hip_runtime.h>

// GRU: H=32, I=1, B=2048, T=1024, fused output Linear(32,1).
// Mapping: 1 batch per 64-lane wave (2048 waves = 2/SIMD). Lane (half, j)
// owns gate rows {r,z,n} of unit j for K-range [16*half, 16*half+16).
// v5: packed-fp32 core. The 48 scalar FMAs/step become 24 v_pk_fma_f32
// (+3 v_pk_mul_f32 chain starters) emitted via inline asm — this both
// halves FMA issue cycles (fp32 peak 157 TF requires pk ops; scalar fma
// peaks at 78.6 TF) and forces the 48 weight values into architectural
// VGPR pairs at every use (v4 showed the allocator parking weights in
// AGPRs: VGPR_Count=48 < the 56 values "pinned"). Biases enter in the
// scalar epilogue so chains need no per-step accumulator-init copies.

constexpr int H  = 32;
constexpr int TT = 1024;
constexpr int BB = 2048;

typedef float v2f __attribute__((ext_vector_type(2)));

__device__ __forceinline__ float rcp_(float a)  { return __builtin_amdgcn_rcpf(a); }
__device__ __forceinline__ float exp2_(float a) { return __builtin_amdgcn_exp2f(a); }
__device__ __forceinline__ float bperm_(int bp, float v) {
    return __uint_as_float((unsigned)__builtin_amdgcn_ds_bpermute(bp, (int)__float_as_uint(v)));
}

#define PK_MUL(d, a, b) asm("v_pk_mul_f32 %0, %1, %2" : "=v"(d) : "v"(a), "v"(b))
#define PK_FMA(d, a, b) asm("v_pk_fma_f32 %0, %1, %2, %0" : "+v"(d) : "v"(a), "v"(b))

__global__ __launch_bounds__(256, 2)
void gru_fused(const float* __restrict__ x,      // [B,T]
               const float* __restrict__ h0,     // [1,B,H]
               const float* __restrict__ W_ih,   // [3H,1]
               const float* __restrict__ W_hh,   // [3H,H]
               const float* __restrict__ b_ih,   // [3H]
               const float* __restrict__ b_hh,   // [3H]
               const float* __restrict__ W_out,  // [1,H]
               const float* __restrict__ b_out,  // [1]
               float* __restrict__ out)          // y[B,T] ++ h_n[B,H]
{
    __shared__ __align__(16) float hbuf[4][64];    // [wave][2 copies of h]
    __shared__ float ybuf[4][33 * 32];             // y transpose, 33-stride

    const int tid  = threadIdx.x;
    const int w    = tid >> 6;
    const int lane = tid & 63;
    const int half = lane >> 5;
    const int j    = lane & 31;
    const int b    = (blockIdx.x << 2) | w;

    const float NL2E = -1.44269504f;   // -log2(e): folded into r,z weights
    const float P2L2 =  2.88539008f;   //  2*log2(e): folded into n weights

    // --- weights: own K-half of rows {j, H+j, 2H+j}, pre-scaled, as float2 ---
    const float* Wrp = &W_hh[(0 * H + j) * H + 16 * half];
    const float* Wzp = &W_hh[(1 * H + j) * H + 16 * half];
    const float* Wnp = &W_hh[(2 * H + j) * H + 16 * half];
    v2f Wr[8], Wz[8], Wn[8];
#pragma unroll
    for (int k = 0; k < 8; ++k) {
        v2f a = ((const v2f*)Wrp)[k];
        v2f c = ((const v2f*)Wzp)[k];
        v2f d = ((const v2f*)Wnp)[k];
        Wr[k] = a * NL2E;
        Wz[k] = c * NL2E;
        Wn[k] = d * P2L2;
    }
    // bias / input-weight terms enter accumulators once (zero on half1)
    const float wir = half ? 0.0f : (W_ih[j] * NL2E);
    const float wiz = half ? 0.0f : (W_ih[H + j] * NL2E);
    const float br  = half ? 0.0f : ((b_ih[j] + b_hh[j]) * NL2E);
    const float bz  = half ? 0.0f : ((b_ih[H + j] + b_hh[H + j]) * NL2E);
    const float bhn = half ? 0.0f : (b_hh[2 * H + j] * P2L2);
    const float win = W_ih[2 * H + j] * P2L2;
    const float bin = b_ih[2 * H + j] * P2L2;
    const float wo  = W_out[j];
    const float bo  = b_out[0];

    float h = h0[b * H + j];

    const float* xb = x + (size_t)b * TT;
    float*       yb = out + (size_t)b * TT;

    float* hw = &hbuf[w][0];
    // half0 reads words 0..15 (h_0..h_15), half1 words 48..63 (h_16..h_31):
    // disjoint bank groups, conflict-free.
    const v2f* hp = (const v2f*)&hbuf[w][48 * half];
    // y transpose: both halves write the SAME value to the same address
    // (h identical post-combine) -> benign; banks distinct across j.
    float* yw = &ybuf[w][j];
    float* yrow = &ybuf[w][0];

    const int bp = (lane ^ 32) << 2;   // ds_bpermute byte addr (xor-32 swap)

#pragma unroll 1
    for (int t0 = 0; t0 < TT; t0 += 32) {
        const float xv = xb[t0 + j];   // lane j holds x[t0+j]

#pragma unroll
        for (int s = 0; s < 32; ++s) {
            hw[lane] = h;
            __builtin_amdgcn_wave_barrier();
            v2f q0 = hp[0], q1 = hp[1], q2 = hp[2], q3 = hp[3];
            v2f q4 = hp[4], q5 = hp[5], q6 = hp[6], q7 = hp[7];

            const float xt = __uint_as_float(
                (unsigned)__builtin_amdgcn_readlane((int)__float_as_uint(xv), s));

            // packed matvec: 3 chains (r,z,n), 1 pk_mul + 7 pk_fma each
            v2f ar, az, an;
            PK_MUL(ar, Wr[0], q0);  PK_MUL(az, Wz[0], q0);  PK_MUL(an, Wn[0], q0);
            PK_FMA(ar, Wr[1], q1);  PK_FMA(az, Wz[1], q1);  PK_FMA(an, Wn[1], q1);
            PK_FMA(ar, Wr[2], q2);  PK_FMA(az, Wz[2], q2);  PK_FMA(an, Wn[2], q2);
            PK_FMA(ar, Wr[3], q3);  PK_FMA(az, Wz[3], q3);  PK_FMA(an, Wn[3], q3);
            PK_FMA(ar, Wr[4], q4);  PK_FMA(az, Wz[4], q4);  PK_FMA(an, Wn[4], q4);
            PK_FMA(ar, Wr[5], q5);  PK_FMA(az, Wz[5], q5);  PK_FMA(an, Wn[5], q5);
            PK_FMA(ar, Wr[6], q6);  PK_FMA(az, Wz[6], q6);  PK_FMA(an, Wn[6], q6);
            PK_FMA(ar, Wr[7], q7);  PK_FMA(az, Wz[7], q7);  PK_FMA(an, Wn[7], q7);

            // epilogue: horizontal add + bias + x-term
            float accr = __builtin_fmaf(xt, wir, (ar.x + ar.y) + br);
            float accz = __builtin_fmaf(xt, wiz, (az.x + az.y) + bz);
            float accn = (an.x + an.y) + bhn;

            // combine the two K-halves (xor-32 swap + add)
            accr += bperm_(bp, accr);
            accz += bperm_(bp, accz);
            accn += bperm_(bp, accn);

            // gates: scales pre-folded; sigmoid = rcp(1+exp2(acc'))
            const float r = rcp_(1.0f + exp2_(accr));
            const float z = rcp_(1.0f + exp2_(accz));
            const float xpn  = __builtin_fmaf(xt, win, bin);
            const float npre = __builtin_fmaf(r, accn, xpn);   // pre-scaled by 2*log2e
            const float n = __builtin_fmaf(-2.0f, rcp_(1.0f + exp2_(npre)), 1.0f);

            h = __builtin_fmaf(z, h - n, n);   // (1-z)*n + z*h

            yw[33 * s] = wo * h;               // constant-offset ds_write
        }

        // amortized y reduction: lane (half,j) sums row j (broadcast across halves)
        __builtin_amdgcn_wave_barrier();
        float s0 = 0.0f, s1 = 0.0f, s2 = 0.0f, s3 = 0.0f;
#pragma unroll
        for (int k = 0; k < 32; k += 4) {
            s0 += yrow[33 * j + k + 0];
            s1 += yrow[33 * j + k + 1];
            s2 += yrow[33 * j + k + 2];
            s3 += yrow[33 * j + k + 3];
        }
        if (half == 0) {
            yb[t0 + j] = (s0 + s1) + (s2 + s3) + bo;
        }
        __builtin_amdgcn_wave_barrier();   // next chunk's writes must not pass reads
    }

    if (half == 0) {
        out[(size_t)BB * TT + b * H + j] = h;   // h_n
    }
}

extern "C" void kernel_launch(void* const* d_in, const int* in_sizes, int n_in,
                              void* d_out, int out_size, void* d_ws, size_t ws_size,
                              hipStream_t stream) {
    const float* x     = (const float*)d_in[0];
    const float* h0    = (const float*)d_in[1];
    const float* W_ih  = (const float*)d_in[2];
    const float* W_hh  = (const float*)d_in[3];
    const float* b_ih  = (const float*)d_in[4];
    const float* b_hh  = (const float*)d_in[5];
    const float* W_out = (const float*)d_in[6];
    const float* b_out = (const float*)d_in[7];
    float* out = (float*)d_out;

    dim3 grid(BB / 4);   // 512 blocks, 4 waves (batches) each
    dim3 block(256);
    gru_fused<<<grid, block, 0, stream>>>(x, h0, W_ih, W_hh, b_ih, b_hh,
                                          W_out, b_out, out);
}